// Round 6
// baseline (627.603 us; speedup 1.0000x reference)
//
#include <hip/hip_runtime.h>

#define DIM 4096
#define HD 128
#define NH 32
#define NKV 8
#define SEQ 2048
#define BATCH 2
#define MTOT (BATCH*SEQ)   // 4096 rows total
#define GK DIM             // K dim of every GEMM

typedef __bf16 bf16;
typedef __bf16 bf16x4 __attribute__((ext_vector_type(4)));
typedef __bf16 bf16x8 __attribute__((ext_vector_type(8)));
typedef float f32x4 __attribute__((ext_vector_type(4)));

__device__ __forceinline__ void gload_lds16(const void* g, void* l) {
    __builtin_amdgcn_global_load_lds(
        (const __attribute__((address_space(1))) void*)g,
        (__attribute__((address_space(3))) void*)l, 16, 0, 0);
}

// ---------------- fp32 -> bf16 flat convert (x) ----------------
__global__ __launch_bounds__(256) void conv_bf16(const float* __restrict__ in,
                                                 bf16* __restrict__ out, int n8) {
    int i = blockIdx.x * 256 + threadIdx.x;
    if (i >= n8) return;
    const float4* p = (const float4*)(in + (size_t)i * 8);
    float4 a = p[0], b = p[1];
    bf16x8 v;
    v[0]=(bf16)a.x; v[1]=(bf16)a.y; v[2]=(bf16)a.z; v[3]=(bf16)a.w;
    v[4]=(bf16)b.x; v[5]=(bf16)b.y; v[6]=(bf16)b.z; v[7]=(bf16)b.w;
    *(bf16x8*)(out + (size_t)i * 8) = v;
}

// ---------------- fp32 [K][N] -> bf16 [N][K] transpose-convert ----------------
__global__ __launch_bounds__(256) void tconv(const float* __restrict__ in,
                                             bf16* __restrict__ out, int N, int K) {
    __shared__ float t[32][33];
    int bx = blockIdx.x, by = blockIdx.y;
    int tx = threadIdx.x, ty = threadIdx.y;
    int col = bx * 32 + tx;
#pragma unroll
    for (int r = 0; r < 4; ++r) {
        int row = by * 32 + ty + r * 8;
        t[ty + r * 8][tx] = in[(size_t)row * N + col];
    }
    __syncthreads();
#pragma unroll
    for (int r = 0; r < 4; ++r) {
        int n = bx * 32 + ty + r * 8;
        int k = by * 32 + tx;
        out[(size_t)n * K + k] = (bf16)t[tx][ty + r * 8];
    }
}

// ---------------- RoPE in-place on bf16 buffer ----------------
__global__ __launch_bounds__(256) void rope_k(bf16* __restrict__ buf, int shift, int n8) {
    int i = blockIdx.x * 256 + threadIdx.x;
    if (i >= n8) return;
    size_t base = (size_t)i * 8;
    int col = (int)(base & ((1u << shift) - 1));
    int pos = (int)((base >> shift) & (SEQ - 1));
    int d0 = col & (HD - 1);
    bf16x8 v = *(const bf16x8*)(buf + base);
    float f[8];
#pragma unroll
    for (int j = 0; j < 8; ++j) f[j] = (float)v[j];
    const float nl2t = -13.287712379549449f / 64.f;  // -log2(theta)/(HD/2)
#pragma unroll
    for (int j = 0; j < 4; ++j) {
        float inv = exp2f(nl2t * (float)((d0 >> 1) + j));
        float ang = (float)pos * inv;
        float sn, cs;
        sincosf(ang, &sn, &cs);
        float x0 = f[2 * j], x1 = f[2 * j + 1];
        f[2 * j]     = x0 * cs - x1 * sn;
        f[2 * j + 1] = x0 * sn + x1 * cs;
    }
    bf16x8 ov;
#pragma unroll
    for (int j = 0; j < 8; ++j) ov[j] = (bf16)f[j];
    *(bf16x8*)(buf + base) = ov;
}

// ---------------- bf16 GEMM: C[M,N] = A[M,K] * Bt[N,K]^T  (m97 structure) ----
// used for the small-N projections (K, V) where the 256^2 grid would underfill.
// B-frags loaded FIRST so the compiler's dataflow lgkmcnt waits are progressive
// (first MFMA needs aF[0]+bF[*]; A-loads later in issue order -> counted waits).
template <bool F32OUT>
__global__ __launch_bounds__(256) void gemm_bt(const bf16* __restrict__ A,
                                               const bf16* __restrict__ Bt,
                                               void* __restrict__ out0, int N) {
    __shared__ alignas(16) bf16 sA[2][128 * 32];
    __shared__ alignas(16) bf16 sB[2][128 * 32];
    const int tid = threadIdx.x;
    const int lane = tid & 63, wid = tid >> 6;
    const int wm = wid >> 1, wn = wid & 1;
    const int m0 = blockIdx.y * 128, n0 = blockIdx.x * 128;

    auto stage = [&](int buf, int kt) {
#pragma unroll
        for (int it = 0; it < 2; ++it) {
            int slot = it * 256 + tid;
            int row = slot >> 2, s = slot & 3;
            gload_lds16(A + (size_t)(m0 + row) * GK + kt * 32 + s * 8, &sA[buf][slot * 8]);
            gload_lds16(Bt + (size_t)(n0 + row) * GK + kt * 32 + s * 8, &sB[buf][slot * 8]);
        }
    };

    f32x4 acc[4][4] = {};
    stage(0, 0);
    __syncthreads();
    int cur = 0;
    for (int kt = 0; kt < GK / 32; ++kt) {
        if (kt + 1 < GK / 32) stage(cur ^ 1, kt + 1);
        bf16x8 bF[4], aF[4];
#pragma unroll
        for (int i = 0; i < 4; ++i)
            bF[i] = *(const bf16x8*)&sB[cur][(wn * 64 + i * 16 + (lane & 15)) * 32 + (lane >> 4) * 8];
#pragma unroll
        for (int i = 0; i < 4; ++i)
            aF[i] = *(const bf16x8*)&sA[cur][(wm * 64 + i * 16 + (lane & 15)) * 32 + (lane >> 4) * 8];
#pragma unroll
        for (int mi = 0; mi < 4; ++mi)
#pragma unroll
            for (int ni = 0; ni < 4; ++ni)
                acc[mi][ni] = __builtin_amdgcn_mfma_f32_16x16x32_bf16(aF[mi], bF[ni], acc[mi][ni], 0, 0, 0);
        __syncthreads();
        cur ^= 1;
    }
#pragma unroll
    for (int mi = 0; mi < 4; ++mi) {
#pragma unroll
        for (int ni = 0; ni < 4; ++ni) {
#pragma unroll
            for (int r = 0; r < 4; ++r) {
                int row = m0 + wm * 64 + mi * 16 + (lane >> 4) * 4 + r;
                int col = n0 + wn * 64 + ni * 16 + (lane & 15);
                float v = acc[mi][ni][r];
                if constexpr (F32OUT) {
                    ((float*)out0)[(size_t)row * N + col] = v;
                } else {
                    ((bf16*)out0)[(size_t)row * N + col] = (bf16)v;
                }
            }
        }
    }
}

// ---------------- 256x256 deep-pipelined GEMM (8-wave, 2 phases/K-tile) -----
// Per phase (one 32-wide K-half): [12 ds_read B-first][stage next region]
// [s_waitcnt vmcnt(4)][s_barrier][32 MFMA w/ compiler-progressive lgkm waits].
// No post-MFMA barrier: the WAR guard (all waves consumed region read at
// phase p-2) is implied by the phase p-1 barrier via program order (each
// wave's p-1 reads/stage precede its own p-1 barrier arrival only after its
// p-2 MFMA). Counted vmcnt never 0 except the last tile. LDS swizzle:
// 128B pair-rows, 16B slot ^= (pairrow & 7); inverse-swizzled global source.
template <bool F32OUT>
__global__ __launch_bounds__(512, 2) void gemm8(const bf16* __restrict__ A,
                                                const bf16* __restrict__ Bt,
                                                void* __restrict__ outp, int N) {
    __shared__ alignas(16) char sA[2][2][16384];
    __shared__ alignas(16) char sB[2][2][16384];
    const int tid = threadIdx.x, lane = tid & 63;
    const int wid = tid >> 6;
    const int wm = wid >> 2, wn = wid & 3;
    const int m0 = blockIdx.y * 256, n0 = blockIdx.x * 256;
    const int lrow = lane & 15, hc = lane >> 4;
    // swizzled per-lane byte offset within a region for frag reads
    const int rowbase = ((lrow >> 1) * 128) +
                        (((((lrow & 1) << 2) | hc) ^ (lrow >> 1)) << 4);
    const int NT = GK / 64;

    auto stageR = [&](int t, int kh) {
#pragma unroll
        for (int it = 0; it < 2; ++it) {
            int sl = it * 512 + tid;              // 16B chunk id 0..1023
            int PRr = sl >> 3, ps = sl & 7;       // pair-row, phys slot
            int lsl = ps ^ (PRr & 7);             // logical slot (involution)
            int r = PRr * 2 + (lsl >> 2);         // logical row 0..255
            int cc = lsl & 3;                     // 16B col-chunk 0..3
            size_t koff = (size_t)t * 64 + kh * 32 + cc * 8;
            gload_lds16(A + (size_t)(m0 + r) * GK + koff, &sA[t & 1][kh][sl * 16]);
            gload_lds16(Bt + (size_t)(n0 + r) * GK + koff, &sB[t & 1][kh][sl * 16]);
        }
    };

    f32x4 acc[8][4] = {};

    // prologue: stage both halves of tile 0 (8 VMEM/thread)
    stageR(0, 0); stageR(0, 1);
    asm volatile("s_waitcnt vmcnt(4)" ::: "memory");   // own (0,0) retired
    __builtin_amdgcn_s_barrier();                      // all waves' (0,0) landed

    for (int t = 0; t < NT; ++t) {
#pragma unroll
        for (int kh = 0; kh < 2; ++kh) {
            const char* Ab = &sA[t & 1][kh][0];
            const char* Bb = &sB[t & 1][kh][0];
            bf16x8 bf[4], af[8];
#pragma unroll
            for (int ni = 0; ni < 4; ++ni)
                bf[ni] = *(const bf16x8*)(Bb + wn * 4096 + ni * 1024 + rowbase);
#pragma unroll
            for (int mi = 0; mi < 8; ++mi)
                af[mi] = *(const bf16x8*)(Ab + wm * 8192 + mi * 1024 + rowbase);
            if (t + 1 < NT) {
                stageR(t + 1, kh);
                asm volatile("s_waitcnt vmcnt(4)" ::: "memory");
            } else {
                asm volatile("s_waitcnt vmcnt(0)" ::: "memory");
            }
            __builtin_amdgcn_s_barrier();
            __builtin_amdgcn_sched_barrier(0);
            __builtin_amdgcn_s_setprio(1);
#pragma unroll
            for (int mi = 0; mi < 8; ++mi)
#pragma unroll
                for (int ni = 0; ni < 4; ++ni)
                    acc[mi][ni] = __builtin_amdgcn_mfma_f32_16x16x32_bf16(af[mi], bf[ni], acc[mi][ni], 0, 0, 0);
            __builtin_amdgcn_s_setprio(0);
        }
    }

    // epilogue
#pragma unroll
    for (int mi = 0; mi < 8; ++mi)
#pragma unroll
        for (int ni = 0; ni < 4; ++ni)
#pragma unroll
            for (int r = 0; r < 4; ++r) {
                int row = m0 + wm * 128 + mi * 16 + hc * 4 + r;
                int col = n0 + wn * 64 + ni * 16 + lrow;
                if constexpr (F32OUT)
                    ((float*)outp)[(size_t)row * N + col] = acc[mi][ni][r];
                else
                    ((bf16*)outp)[(size_t)row * N + col] = (bf16)acc[mi][ni][r];
            }
}

// ---------------- flash attention, GQA, causal ----------------
// grid: 512 = b(2) * h(32) * pair(8); 8 waves x 16 q-rows = 128 q-rows/pass;
// each block runs two passes (q-tile pr and 15-pr) -> exactly 34 KV rounds each.
// Swapped QK^T (S^T): softmax rows lane-local, P-writes packed b64.
__global__ __launch_bounds__(512, 4) void attn_fwd(const bf16* __restrict__ q,
                                                   const bf16* __restrict__ k,
                                                   const bf16* __restrict__ vt,
                                                   bf16* __restrict__ o) {
    __shared__ alignas(16) bf16 sK[2][64 * 128];   // [kv][d], XOR-swizzled source
    __shared__ alignas(16) bf16 sV[2][128 * 64];   // [d][kv], XOR-swizzled source
    __shared__ alignas(16) bf16 sP[8][16 * 64];    // per-wave P[q][kv], swizzled
    const int tid = threadIdx.x, lane = tid & 63, wid = tid >> 6;
    const int bi = blockIdx.x;
    const int pr = bi & 7;
    const int h = (bi >> 3) & 31;
    const int b = bi >> 8;
    const int kvh = h >> 2;
    const float scale = 0.08838834764831845f;  // 1/sqrt(128)

    const bf16* kb0 = k + (size_t)b * SEQ * (NKV * HD) + kvh * HD;
    const bf16* vb0 = vt + (size_t)(kvh * HD) * MTOT + (size_t)b * SEQ;

    auto stage = [&](int bf, int tt) {
        // K tile [64][128]: 1024 16B-slots, src slot = phys ^ (row&7)
#pragma unroll
        for (int it = 0; it < 2; ++it) {
            int slot = it * 512 + tid;
            int row = slot >> 4, s = slot & 15;
            gload_lds16(kb0 + (size_t)(tt * 64 + row) * (NKV * HD) + ((s ^ (row & 7)) * 8),
                        &sK[bf][slot * 8]);
        }
        // V^T tile [128][64] from vt[vdim][token] (row stride MTOT)
#pragma unroll
        for (int it = 0; it < 2; ++it) {
            int slot = it * 512 + tid;
            int row = slot >> 3, s = slot & 7;
            gload_lds16(vb0 + (size_t)row * MTOT + tt * 64 + ((s ^ (row & 7)) * 8),
                        &sV[bf][slot * 8]);
        }
    };

    auto pass = [&](int qt) {
        const int qb0 = qt * 128;
        const int nt = 2 * qt + 2;
        const bf16* qp = q + ((size_t)(b * SEQ + qb0 + wid * 16 + (lane & 15))) * DIM
                           + h * HD + (lane >> 4) * 8;
        bf16x8 aQ[4];
#pragma unroll
        for (int ks = 0; ks < 4; ++ks) aQ[ks] = *(const bf16x8*)(qp + ks * 32);

        f32x4 accO[8] = {};
        float m_r = -1e30f, l_r = 0.f;   // per-lane: q-col = lane&15 (uniform over hi)
        const int qglob = qb0 + wid * 16 + (lane & 15);
        char* pb = (char*)&sP[wid][0];
        const int q7s = (lane & 7) << 4;
        const int hi = lane >> 4;

        stage(0, 0);
        __syncthreads();
        int cur = 0;
        for (int tt = 0; tt < nt; ++tt) {
            if (tt + 1 < nt) stage(cur ^ 1, tt + 1);
            // skip tiles fully above this wave's diagonal (identity contribution)
            if (tt * 64 <= qb0 + wid * 16 + 15) {
                // S^T = mfma(K, Q): frag nt2 -> rows kv = tt*64+nt2*16+hi*4+r, col q = lane&15
                f32x4 accS[4] = {};
#pragma unroll
                for (int nt2 = 0; nt2 < 4; ++nt2) {
                    int kr = nt2 * 16 + (lane & 15);
#pragma unroll
                    for (int ks = 0; ks < 4; ++ks) {
                        int slog = ks * 4 + hi;
                        bf16x8 bK = *(const bf16x8*)&sK[cur][kr * 128 + ((slog ^ (kr & 7)) * 8)];
                        accS[nt2] = __builtin_amdgcn_mfma_f32_16x16x32_bf16(bK, aQ[ks], accS[nt2], 0, 0, 0);
                    }
                }

                // scale + causal mask + lane-local max over 16 kv values
                const bool diag = (tt * 64 + 63 > qb0 + wid * 16);
                const int kvb = tt * 64 + hi * 4;
                float mx = -1e30f;
#pragma unroll
                for (int nt2 = 0; nt2 < 4; ++nt2)
#pragma unroll
                    for (int r = 0; r < 4; ++r) {
                        float v = accS[nt2][r] * scale;
                        if (diag && (kvb + nt2 * 16 + r > qglob)) v = -1e30f;
                        accS[nt2][r] = v;
                        mx = fmaxf(mx, v);
                    }
                mx = fmaxf(mx, __shfl_xor(mx, 16, 64));
                mx = fmaxf(mx, __shfl_xor(mx, 32, 64));

                float mn = fmaxf(m_r, mx);
                float al = __expf(m_r - mn);
                m_r = mn;
                float rs = 0.f;
#pragma unroll
                for (int nt2 = 0; nt2 < 4; ++nt2)
#pragma unroll
                    for (int r = 0; r < 4; ++r) {
                        float p = __expf(accS[nt2][r] - mn);
                        accS[nt2][r] = p;
                        rs += p;
                    }
                rs += __shfl_xor(rs, 16, 64);
                rs += __shfl_xor(rs, 32, 64);
                l_r = l_r * al + rs;

                // rescale accO: its q-row for reg r is hi*4+r -> fetch al from lane hi*4+r
                float al4[4];
#pragma unroll
                for (int r = 0; r < 4; ++r) al4[r] = __shfl(al, hi * 4 + r, 64);
#pragma unroll
                for (int d2 = 0; d2 < 8; ++d2)
#pragma unroll
                    for (int r = 0; r < 4; ++r) accO[d2][r] *= al4[r];

                // P-write: lane holds 4 contiguous kv per frag -> b64 stores
                // byte = q*128 + ((kvl*2) ^ ((q&7)<<4)), q = lane&15
#pragma unroll
                for (int nt2 = 0; nt2 < 4; ++nt2) {
                    bf16x4 pv;
                    pv[0] = (bf16)accS[nt2][0]; pv[1] = (bf16)accS[nt2][1];
                    pv[2] = (bf16)accS[nt2][2]; pv[3] = (bf16)accS[nt2][3];
                    *(bf16x4*)(pb + (lane & 15) * 128 + ((nt2 * 32 + hi * 8) ^ q7s)) = pv;
                }

                // PV: O[16 x 128] += P[16 x 64] * V[64 x 128]
                bf16x8 aP[2];
#pragma unroll
                for (int kk = 0; kk < 2; ++kk)
                    aP[kk] = *(const bf16x8*)(pb + (lane & 15) * 128 + ((kk * 64 + hi * 16) ^ q7s));
#pragma unroll
                for (int d2 = 0; d2 < 8; ++d2) {
#pragma unroll
                    for (int kk = 0; kk < 2; ++kk) {
                        int dv = d2 * 16 + (lane & 15);
                        int phys = (kk * 4 + hi) ^ (dv & 7);
                        bf16x8 bV = *(const bf16x8*)&sV[cur][dv * 64 + phys * 8];
                        accO[d2] = __builtin_amdgcn_mfma_f32_16x16x32_bf16(aP[kk], bV, accO[d2], 0, 0, 0);
                    }
                }
            }
            __syncthreads();
            cur ^= 1;
        }

        // epilogue: normalize + store bf16 (accO q-row for reg r = hi*4+r)
        float linv[4];
#pragma unroll
        for (int r = 0; r < 4; ++r) linv[r] = 1.f / __shfl(l_r, hi * 4 + r, 64);
        size_t orow = (size_t)(b * SEQ + qb0 + wid * 16 + hi * 4) * DIM
                    + h * HD + (lane & 15);
#pragma unroll
        for (int d2 = 0; d2 < 8; ++d2)
#pragma unroll
            for (int r = 0; r < 4; ++r)
                o[orow + (size_t)r * DIM + d2 * 16] = (bf16)(accO[d2][r] * linv[r]);
    };

    pass(pr);
    pass(15 - pr);
}

// ---------------- launch ----------------
extern "C" void kernel_launch(void* const* d_in, const int* in_sizes, int n_in,
                              void* d_out, int out_size, void* d_ws, size_t ws_size,
                              hipStream_t stream) {
    const float* x  = (const float*)d_in[0];
    const float* wq = (const float*)d_in[1];
    const float* wk = (const float*)d_in[2];
    const float* wv = (const float*)d_in[3];
    const float* wo = (const float*)d_in[4];
    float* out = (float*)d_out;

    char* ws = (char*)d_ws;
    size_t off = 0;
    bf16* xb  = (bf16*)(ws + off); off += (size_t)MTOT * DIM * 2;   // 32 MiB (reused as attn_out)
    bf16* wqt = (bf16*)(ws + off); off += (size_t)DIM * DIM * 2;    // 32 MiB (reused as wo_t)
    bf16* wkt = (bf16*)(ws + off); off += (size_t)1024 * DIM * 2;   // 8 MiB
    bf16* wvt = (bf16*)(ws + off); off += (size_t)1024 * DIM * 2;   // 8 MiB
    bf16* qb  = (bf16*)(ws + off); off += (size_t)MTOT * DIM * 2;   // 32 MiB
    bf16* kb  = (bf16*)(ws + off); off += (size_t)MTOT * 1024 * 2;  // 8 MiB
    bf16* vtb = (bf16*)(ws + off); off += (size_t)MTOT * 1024 * 2;  // 8 MiB  V^T [1024][4096]
    bf16* ao = xb;  // attention output reuses x_bf16

    dim3 tb(32, 8);
    conv_bf16<<<(MTOT * DIM / 8) / 256, 256, 0, stream>>>(x, xb, MTOT * DIM / 8);
    tconv<<<dim3(DIM / 32, DIM / 32), tb, 0, stream>>>(wq, wqt, DIM, DIM);
    tconv<<<dim3(1024 / 32, DIM / 32), tb, 0, stream>>>(wk, wkt, 1024, DIM);
    tconv<<<dim3(1024 / 32, DIM / 32), tb, 0, stream>>>(wv, wvt, 1024, DIM);

    // Q proj: 4096x4096x4096 on the 256^2 deep-pipelined kernel (256 blocks)
    gemm8<false><<<dim3(DIM / 256, MTOT / 256), 512, 0, stream>>>(xb, wqt, qb, DIM);
    // K proj (N=1024) and V^T proj (M=1024) on the 128^2 kernel (full 256-block grids)
    gemm_bt<false><<<dim3(1024 / 128, MTOT / 128), 256, 0, stream>>>(xb, wkt, kb, 1024);
    gemm_bt<false><<<dim3(MTOT / 128, 1024 / 128), 256, 0, stream>>>(wvt, xb, vtb, MTOT);

    rope_k<<<(MTOT * DIM / 8) / 256, 256, 0, stream>>>(qb, 12, MTOT * DIM / 8);
    rope_k<<<(MTOT * 1024 / 8) / 256, 256, 0, stream>>>(kb, 10, MTOT * 1024 / 8);

    tconv<<<dim3(DIM / 32, DIM / 32), tb, 0, stream>>>(wo, wqt, DIM, DIM);  // wo_t -> wqt space

    attn_fwd<<<BATCH * NH * 8, 512, 0, stream>>>(qb, kb, vtb, ao);

    // out proj: fp32 output on the 256^2 kernel
    gemm8<true><<<dim3(DIM / 256, MTOT / 256), 512, 0, stream>>>(ao, wqt, out, DIM);
}

// Round 7
// 609.005 us; speedup vs baseline: 1.0305x; 1.0305x over previous
//
#include <hip/hip_runtime.h>

#define DIM 4096
#define HD 128
#define NH 32
#define NKV 8
#define SEQ 2048
#define BATCH 2
#define MTOT (BATCH*SEQ)   // 4096 rows total
#define GK DIM             // K dim of every GEMM

typedef __bf16 bf16;
typedef __bf16 bf16x4 __attribute__((ext_vector_type(4)));
typedef __bf16 bf16x8 __attribute__((ext_vector_type(8)));
typedef float f32x4 __attribute__((ext_vector_type(4)));

__device__ __forceinline__ void gload_lds16(const void* g, void* l) {
    __builtin_amdgcn_global_load_lds(
        (const __attribute__((address_space(1))) void*)g,
        (__attribute__((address_space(3))) void*)l, 16, 0, 0);
}

// ---------------- fp32 -> bf16 flat convert (x) ----------------
__global__ __launch_bounds__(256) void conv_bf16(const float* __restrict__ in,
                                                 bf16* __restrict__ out, int n8) {
    int i = blockIdx.x * 256 + threadIdx.x;
    if (i >= n8) return;
    const float4* p = (const float4*)(in + (size_t)i * 8);
    float4 a = p[0], b = p[1];
    bf16x8 v;
    v[0]=(bf16)a.x; v[1]=(bf16)a.y; v[2]=(bf16)a.z; v[3]=(bf16)a.w;
    v[4]=(bf16)b.x; v[5]=(bf16)b.y; v[6]=(bf16)b.z; v[7]=(bf16)b.w;
    *(bf16x8*)(out + (size_t)i * 8) = v;
}

// ---------------- fp32 [K][N] -> bf16 [N][K] transpose-convert ----------------
__global__ __launch_bounds__(256) void tconv(const float* __restrict__ in,
                                             bf16* __restrict__ out, int N, int K) {
    __shared__ float t[32][33];
    int bx = blockIdx.x, by = blockIdx.y;
    int tx = threadIdx.x, ty = threadIdx.y;
    int col = bx * 32 + tx;
#pragma unroll
    for (int r = 0; r < 4; ++r) {
        int row = by * 32 + ty + r * 8;
        t[ty + r * 8][tx] = in[(size_t)row * N + col];
    }
    __syncthreads();
#pragma unroll
    for (int r = 0; r < 4; ++r) {
        int n = bx * 32 + ty + r * 8;
        int k = by * 32 + tx;
        out[(size_t)n * K + k] = (bf16)t[tx][ty + r * 8];
    }
}

// ---------------- RoPE in-place on bf16 buffer (optional output scale) ------
__global__ __launch_bounds__(256) void rope_k(bf16* __restrict__ buf, int shift,
                                              int n8, float oscale) {
    int i = blockIdx.x * 256 + threadIdx.x;
    if (i >= n8) return;
    size_t base = (size_t)i * 8;
    int col = (int)(base & ((1u << shift) - 1));
    int pos = (int)((base >> shift) & (SEQ - 1));
    int d0 = col & (HD - 1);
    bf16x8 v = *(const bf16x8*)(buf + base);
    float f[8];
#pragma unroll
    for (int j = 0; j < 8; ++j) f[j] = (float)v[j];
    const float nl2t = -13.287712379549449f / 64.f;  // -log2(theta)/(HD/2)
#pragma unroll
    for (int j = 0; j < 4; ++j) {
        float inv = exp2f(nl2t * (float)((d0 >> 1) + j));
        float ang = (float)pos * inv;
        float sn, cs;
        sincosf(ang, &sn, &cs);
        float x0 = f[2 * j], x1 = f[2 * j + 1];
        f[2 * j]     = x0 * cs - x1 * sn;
        f[2 * j + 1] = x0 * sn + x1 * cs;
    }
    bf16x8 ov;
#pragma unroll
    for (int j = 0; j < 8; ++j) ov[j] = (bf16)(f[j] * oscale);
    *(bf16x8*)(buf + base) = ov;
}

// ---------------- bf16 GEMM: C[M,N] = A[M,K] * Bt[N,K]^T  (m97 structure) ----
template <bool F32OUT>
__global__ __launch_bounds__(256) void gemm_bt(const bf16* __restrict__ A,
                                               const bf16* __restrict__ Bt,
                                               void* __restrict__ out0, int N) {
    __shared__ alignas(16) bf16 sA[2][128 * 32];
    __shared__ alignas(16) bf16 sB[2][128 * 32];
    const int tid = threadIdx.x;
    const int lane = tid & 63, wid = tid >> 6;
    const int wm = wid >> 1, wn = wid & 1;
    const int m0 = blockIdx.y * 128, n0 = blockIdx.x * 128;

    auto stage = [&](int buf, int kt) {
#pragma unroll
        for (int it = 0; it < 2; ++it) {
            int slot = it * 256 + tid;
            int row = slot >> 2, s = slot & 3;
            gload_lds16(A + (size_t)(m0 + row) * GK + kt * 32 + s * 8, &sA[buf][slot * 8]);
            gload_lds16(Bt + (size_t)(n0 + row) * GK + kt * 32 + s * 8, &sB[buf][slot * 8]);
        }
    };

    f32x4 acc[4][4] = {};
    stage(0, 0);
    __syncthreads();
    int cur = 0;
    for (int kt = 0; kt < GK / 32; ++kt) {
        if (kt + 1 < GK / 32) stage(cur ^ 1, kt + 1);
        bf16x8 bF[4], aF[4];
#pragma unroll
        for (int i = 0; i < 4; ++i)
            bF[i] = *(const bf16x8*)&sB[cur][(wn * 64 + i * 16 + (lane & 15)) * 32 + (lane >> 4) * 8];
#pragma unroll
        for (int i = 0; i < 4; ++i)
            aF[i] = *(const bf16x8*)&sA[cur][(wm * 64 + i * 16 + (lane & 15)) * 32 + (lane >> 4) * 8];
#pragma unroll
        for (int mi = 0; mi < 4; ++mi)
#pragma unroll
            for (int ni = 0; ni < 4; ++ni)
                acc[mi][ni] = __builtin_amdgcn_mfma_f32_16x16x32_bf16(aF[mi], bF[ni], acc[mi][ni], 0, 0, 0);
        __syncthreads();
        cur ^= 1;
    }
#pragma unroll
    for (int mi = 0; mi < 4; ++mi) {
#pragma unroll
        for (int ni = 0; ni < 4; ++ni) {
#pragma unroll
            for (int r = 0; r < 4; ++r) {
                int row = m0 + wm * 64 + mi * 16 + (lane >> 4) * 4 + r;
                int col = n0 + wn * 64 + ni * 16 + (lane & 15);
                float v = acc[mi][ni][r];
                if constexpr (F32OUT) {
                    ((float*)out0)[(size_t)row * N + col] = v;
                } else {
                    ((bf16*)out0)[(size_t)row * N + col] = (bf16)v;
                }
            }
        }
    }
}

// ---------------- 256x256 deep-pipelined GEMM (8-wave, 2 phases/K-tile) -----
template <bool F32OUT>
__global__ __launch_bounds__(512, 2) void gemm8(const bf16* __restrict__ A,
                                                const bf16* __restrict__ Bt,
                                                void* __restrict__ outp, int N) {
    __shared__ alignas(16) char sA[2][2][16384];
    __shared__ alignas(16) char sB[2][2][16384];
    const int tid = threadIdx.x, lane = tid & 63;
    const int wid = tid >> 6;
    const int wm = wid >> 2, wn = wid & 3;
    const int m0 = blockIdx.y * 256, n0 = blockIdx.x * 256;
    const int lrow = lane & 15, hc = lane >> 4;
    // swizzled per-lane byte offset within a region for frag reads
    const int rowbase = ((lrow >> 1) * 128) +
                        (((((lrow & 1) << 2) | hc) ^ (lrow >> 1)) << 4);
    const int NT = GK / 64;

    auto stageR = [&](int t, int kh) {
#pragma unroll
        for (int it = 0; it < 2; ++it) {
            int sl = it * 512 + tid;              // 16B chunk id 0..1023
            int PRr = sl >> 3, ps = sl & 7;       // pair-row, phys slot
            int lsl = ps ^ (PRr & 7);             // logical slot (involution)
            int r = PRr * 2 + (lsl >> 2);         // logical row 0..255
            int cc = lsl & 3;                     // 16B col-chunk 0..3
            size_t koff = (size_t)t * 64 + kh * 32 + cc * 8;
            gload_lds16(A + (size_t)(m0 + r) * GK + koff, &sA[t & 1][kh][sl * 16]);
            gload_lds16(Bt + (size_t)(n0 + r) * GK + koff, &sB[t & 1][kh][sl * 16]);
        }
    };

    f32x4 acc[8][4] = {};

    // prologue: stage both halves of tile 0 (8 VMEM/thread)
    stageR(0, 0); stageR(0, 1);
    asm volatile("s_waitcnt vmcnt(4)" ::: "memory");   // own (0,0) retired
    __builtin_amdgcn_s_barrier();                      // all waves' (0,0) landed

    for (int t = 0; t < NT; ++t) {
#pragma unroll
        for (int kh = 0; kh < 2; ++kh) {
            const char* Ab = &sA[t & 1][kh][0];
            const char* Bb = &sB[t & 1][kh][0];
            bf16x8 bf[4], af[8];
#pragma unroll
            for (int ni = 0; ni < 4; ++ni)
                bf[ni] = *(const bf16x8*)(Bb + wn * 4096 + ni * 1024 + rowbase);
#pragma unroll
            for (int mi = 0; mi < 8; ++mi)
                af[mi] = *(const bf16x8*)(Ab + wm * 8192 + mi * 1024 + rowbase);
            if (t + 1 < NT) {
                stageR(t + 1, kh);
                asm volatile("s_waitcnt vmcnt(4)" ::: "memory");
            } else {
                asm volatile("s_waitcnt vmcnt(0)" ::: "memory");
            }
            __builtin_amdgcn_s_barrier();
            __builtin_amdgcn_sched_barrier(0);
            __builtin_amdgcn_s_setprio(1);
#pragma unroll
            for (int mi = 0; mi < 8; ++mi)
#pragma unroll
                for (int ni = 0; ni < 4; ++ni)
                    acc[mi][ni] = __builtin_amdgcn_mfma_f32_16x16x32_bf16(af[mi], bf[ni], acc[mi][ni], 0, 0, 0);
            __builtin_amdgcn_s_setprio(0);
        }
    }

    // epilogue
#pragma unroll
    for (int mi = 0; mi < 8; ++mi)
#pragma unroll
        for (int ni = 0; ni < 4; ++ni)
#pragma unroll
            for (int r = 0; r < 4; ++r) {
                int row = m0 + wm * 128 + mi * 16 + hc * 4 + r;
                int col = n0 + wn * 64 + ni * 16 + lrow;
                if constexpr (F32OUT)
                    ((float*)outp)[(size_t)row * N + col] = acc[mi][ni][r];
                else
                    ((bf16*)outp)[(size_t)row * N + col] = (bf16)acc[mi][ni][r];
            }
}

// ---------------- flash attention, GQA, causal ----------------
// grid: 512 = b(2) * h(32) * pair(8); 8 waves x 16 q-rows = 128 q-rows/pass;
// each block runs two passes (q-tile pr and 15-pr) -> exactly 34 KV rounds each.
// Swapped QK^T (S^T). Q is pre-scaled by 1/sqrt(d)*log2(e) in rope pass ->
// softmax runs in exp2 domain with raw v_exp_f32. Wave-uniform diag split +
// defer-max (THR=8): rescale only when the tile max advances the running max.
__global__ __launch_bounds__(512, 4) void attn_fwd(const bf16* __restrict__ q,
                                                   const bf16* __restrict__ k,
                                                   const bf16* __restrict__ vt,
                                                   bf16* __restrict__ o) {
    __shared__ alignas(16) bf16 sK[2][64 * 128];   // [kv][d], XOR-swizzled source
    __shared__ alignas(16) bf16 sV[2][128 * 64];   // [d][kv], XOR-swizzled source
    __shared__ alignas(16) bf16 sP[8][16 * 64];    // per-wave P[q][kv], swizzled
    const int tid = threadIdx.x, lane = tid & 63, wid = tid >> 6;
    const int bi = blockIdx.x;
    const int pr = bi & 7;
    const int h = (bi >> 3) & 31;
    const int b = bi >> 8;
    const int kvh = h >> 2;

    const bf16* kb0 = k + (size_t)b * SEQ * (NKV * HD) + kvh * HD;
    const bf16* vb0 = vt + (size_t)(kvh * HD) * MTOT + (size_t)b * SEQ;

    auto stage = [&](int bf, int tt) {
#pragma unroll
        for (int it = 0; it < 2; ++it) {
            int slot = it * 512 + tid;
            int row = slot >> 4, s = slot & 15;
            gload_lds16(kb0 + (size_t)(tt * 64 + row) * (NKV * HD) + ((s ^ (row & 7)) * 8),
                        &sK[bf][slot * 8]);
        }
#pragma unroll
        for (int it = 0; it < 2; ++it) {
            int slot = it * 512 + tid;
            int row = slot >> 3, s = slot & 7;
            gload_lds16(vb0 + (size_t)row * MTOT + tt * 64 + ((s ^ (row & 7)) * 8),
                        &sV[bf][slot * 8]);
        }
    };

    auto pass = [&](int qt) {
        const int qb0 = qt * 128;
        const int nt = 2 * qt + 2;
        const int qw = qb0 + wid * 16;        // wave's first q row (16-aligned)
        const bf16* qp = q + ((size_t)(b * SEQ + qw + (lane & 15))) * DIM
                           + h * HD + (lane >> 4) * 8;
        bf16x8 aQ[4];
#pragma unroll
        for (int ks = 0; ks < 4; ++ks) aQ[ks] = *(const bf16x8*)(qp + ks * 32);

        f32x4 accO[8] = {};
        float m_r = -1e30f, l_r = 0.f;   // per-lane: q-col = lane&15 (uniform over hi)
        const int qglob = qw + (lane & 15);
        char* pb = (char*)&sP[wid][0];
        const int q7s = (lane & 7) << 4;
        const int hi = lane >> 4;

        stage(0, 0);
        __syncthreads();
        int cur = 0;
        for (int tt = 0; tt < nt; ++tt) {
            if (tt + 1 < nt) stage(cur ^ 1, tt + 1);
            // skip tiles fully above this wave's rows (t0 and qw both 16-aligned)
            if (tt * 64 <= qw) {
                // S^T = mfma(K, Q): frag nt2 -> kv = tt*64+nt2*16+hi*4+r, col q = lane&15
                f32x4 accS[4] = {};
#pragma unroll
                for (int nt2 = 0; nt2 < 4; ++nt2) {
                    int kr = nt2 * 16 + (lane & 15);
#pragma unroll
                    for (int ks = 0; ks < 4; ++ks) {
                        int slog = ks * 4 + hi;
                        bf16x8 bK = *(const bf16x8*)&sK[cur][kr * 128 + ((slog ^ (kr & 7)) * 8)];
                        accS[nt2] = __builtin_amdgcn_mfma_f32_16x16x32_bf16(bK, aQ[ks], accS[nt2], 0, 0, 0);
                    }
                }

                // lane-local max over 16 kv values; mask only on diagonal tiles
                const bool diag = (tt * 64 + 63 > qw);
                float mx = -1e30f;
                if (diag) {
                    const int kvb = tt * 64 + hi * 4;
#pragma unroll
                    for (int nt2 = 0; nt2 < 4; ++nt2)
#pragma unroll
                        for (int r = 0; r < 4; ++r) {
                            float v = accS[nt2][r];
                            if (kvb + nt2 * 16 + r > qglob) v = -1e30f;
                            accS[nt2][r] = v;
                            mx = fmaxf(mx, v);
                        }
                } else {
#pragma unroll
                    for (int nt2 = 0; nt2 < 4; ++nt2)
#pragma unroll
                        for (int r = 0; r < 4; ++r) mx = fmaxf(mx, accS[nt2][r]);
                }
                mx = fmaxf(mx, __shfl_xor(mx, 16, 64));
                mx = fmaxf(mx, __shfl_xor(mx, 32, 64));

                // defer-max: only rescale when tile max advances past m_r + 8
                if (!__all(mx <= m_r + 8.f)) {
                    float mn = fmaxf(m_r, mx);
                    float al = __builtin_amdgcn_exp2f(m_r - mn);
                    m_r = mn;
                    l_r *= al;
                    float al4[4];
#pragma unroll
                    for (int r = 0; r < 4; ++r) al4[r] = __shfl(al, hi * 4 + r, 64);
#pragma unroll
                    for (int d2 = 0; d2 < 8; ++d2)
#pragma unroll
                        for (int r = 0; r < 4; ++r) accO[d2][r] *= al4[r];
                }

                float rs = 0.f;
#pragma unroll
                for (int nt2 = 0; nt2 < 4; ++nt2)
#pragma unroll
                    for (int r = 0; r < 4; ++r) {
                        float p = __builtin_amdgcn_exp2f(accS[nt2][r] - m_r);
                        accS[nt2][r] = p;
                        rs += p;
                    }
                rs += __shfl_xor(rs, 16, 64);
                rs += __shfl_xor(rs, 32, 64);
                l_r += rs;

                // P-write: lane holds 4 contiguous kv per frag -> b64 stores
#pragma unroll
                for (int nt2 = 0; nt2 < 4; ++nt2) {
                    bf16x4 pv;
                    pv[0] = (bf16)accS[nt2][0]; pv[1] = (bf16)accS[nt2][1];
                    pv[2] = (bf16)accS[nt2][2]; pv[3] = (bf16)accS[nt2][3];
                    *(bf16x4*)(pb + (lane & 15) * 128 + ((nt2 * 32 + hi * 8) ^ q7s)) = pv;
                }

                // PV: O[16 x 128] += P[16 x 64] * V[64 x 128]
                bf16x8 aP[2];
#pragma unroll
                for (int kk = 0; kk < 2; ++kk)
                    aP[kk] = *(const bf16x8*)(pb + (lane & 15) * 128 + ((kk * 64 + hi * 16) ^ q7s));
#pragma unroll
                for (int d2 = 0; d2 < 8; ++d2) {
#pragma unroll
                    for (int kk = 0; kk < 2; ++kk) {
                        int dv = d2 * 16 + (lane & 15);
                        int phys = (kk * 4 + hi) ^ (dv & 7);
                        bf16x8 bV = *(const bf16x8*)&sV[cur][dv * 64 + phys * 8];
                        accO[d2] = __builtin_amdgcn_mfma_f32_16x16x32_bf16(aP[kk], bV, accO[d2], 0, 0, 0);
                    }
                }
            }
            __syncthreads();
            cur ^= 1;
        }

        // epilogue: normalize + store bf16 (accO q-row for reg r = hi*4+r)
        float linv[4];
#pragma unroll
        for (int r = 0; r < 4; ++r) linv[r] = 1.f / __shfl(l_r, hi * 4 + r, 64);
        size_t orow = (size_t)(b * SEQ + qb0 + wid * 16 + hi * 4) * DIM
                    + h * HD + (lane & 15);
#pragma unroll
        for (int d2 = 0; d2 < 8; ++d2)
#pragma unroll
            for (int r = 0; r < 4; ++r)
                o[orow + (size_t)r * DIM + d2 * 16] = (bf16)(accO[d2][r] * linv[r]);
    };

    pass(pr);
    pass(15 - pr);
}

// ---------------- launch ----------------
extern "C" void kernel_launch(void* const* d_in, const int* in_sizes, int n_in,
                              void* d_out, int out_size, void* d_ws, size_t ws_size,
                              hipStream_t stream) {
    const float* x  = (const float*)d_in[0];
    const float* wq = (const float*)d_in[1];
    const float* wk = (const float*)d_in[2];
    const float* wv = (const float*)d_in[3];
    const float* wo = (const float*)d_in[4];
    float* out = (float*)d_out;

    char* ws = (char*)d_ws;
    size_t off = 0;
    bf16* xb  = (bf16*)(ws + off); off += (size_t)MTOT * DIM * 2;   // 32 MiB (reused as attn_out)
    bf16* wqt = (bf16*)(ws + off); off += (size_t)DIM * DIM * 2;    // 32 MiB (reused as wo_t)
    bf16* wkt = (bf16*)(ws + off); off += (size_t)1024 * DIM * 2;   // 8 MiB
    bf16* wvt = (bf16*)(ws + off); off += (size_t)1024 * DIM * 2;   // 8 MiB
    bf16* qb  = (bf16*)(ws + off); off += (size_t)MTOT * DIM * 2;   // 32 MiB
    bf16* kb  = (bf16*)(ws + off); off += (size_t)MTOT * 1024 * 2;  // 8 MiB
    bf16* vtb = (bf16*)(ws + off); off += (size_t)MTOT * 1024 * 2;  // 8 MiB  V^T [1024][4096]
    bf16* ao = xb;  // attention output reuses x_bf16

    // 1/sqrt(HD) * log2(e): folds softmax scale + exp->exp2 conversion into Q
    const float SCALE2 = 0.08838834764831845f * 1.44269504088896340f;

    dim3 tb(32, 8);
    conv_bf16<<<(MTOT * DIM / 8) / 256, 256, 0, stream>>>(x, xb, MTOT * DIM / 8);
    tconv<<<dim3(DIM / 32, DIM / 32), tb, 0, stream>>>(wq, wqt, DIM, DIM);
    tconv<<<dim3(1024 / 32, DIM / 32), tb, 0, stream>>>(wk, wkt, 1024, DIM);
    tconv<<<dim3(1024 / 32, DIM / 32), tb, 0, stream>>>(wv, wvt, 1024, DIM);

    // Q proj: 4096x4096x4096 on the 256^2 deep-pipelined kernel (256 blocks)
    gemm8<false><<<dim3(DIM / 256, MTOT / 256), 512, 0, stream>>>(xb, wqt, qb, DIM);
    // K proj (N=1024) and V^T proj (M=1024) on the 128^2 kernel (full 256-block grids)
    gemm_bt<false><<<dim3(1024 / 128, MTOT / 128), 256, 0, stream>>>(xb, wkt, kb, 1024);
    gemm_bt<false><<<dim3(MTOT / 128, 1024 / 128), 256, 0, stream>>>(wvt, xb, vtb, MTOT);

    rope_k<<<(MTOT * DIM / 8) / 256, 256, 0, stream>>>(qb, 12, MTOT * DIM / 8, SCALE2);
    rope_k<<<(MTOT * 1024 / 8) / 256, 256, 0, stream>>>(kb, 10, MTOT * 1024 / 8, 1.0f);

    tconv<<<dim3(DIM / 32, DIM / 32), tb, 0, stream>>>(wo, wqt, DIM, DIM);  // wo_t -> wqt space

    attn_fwd<<<BATCH * NH * 8, 512, 0, stream>>>(qb, kb, vtb, ao);

    // out proj: fp32 output on the 256^2 kernel
    gemm8<true><<<dim3(DIM / 256, MTOT / 256), 512, 0, stream>>>(ao, wqt, out, DIM);
}

// Round 8
// 542.479 us; speedup vs baseline: 1.1569x; 1.1226x over previous
//
#include <hip/hip_runtime.h>

#define DIM 4096
#define HD 128
#define NH 32
#define NKV 8
#define SEQ 2048
#define BATCH 2
#define MTOT (BATCH*SEQ)   // 4096 rows total
#define GK DIM             // K dim of every GEMM

typedef __bf16 bf16;
typedef __bf16 bf16x4 __attribute__((ext_vector_type(4)));
typedef __bf16 bf16x8 __attribute__((ext_vector_type(8)));
typedef float f32x4 __attribute__((ext_vector_type(4)));

__device__ __forceinline__ void gload_lds16(const void* g, void* l) {
    __builtin_amdgcn_global_load_lds(
        (const __attribute__((address_space(1))) void*)g,
        (__attribute__((address_space(3))) void*)l, 16, 0, 0);
}

// ---------------- fp32 -> bf16 flat convert (x) ----------------
__global__ __launch_bounds__(256) void conv_bf16(const float* __restrict__ in,
                                                 bf16* __restrict__ out, int n8) {
    int i = blockIdx.x * 256 + threadIdx.x;
    if (i >= n8) return;
    const float4* p = (const float4*)(in + (size_t)i * 8);
    float4 a = p[0], b = p[1];
    bf16x8 v;
    v[0]=(bf16)a.x; v[1]=(bf16)a.y; v[2]=(bf16)a.z; v[3]=(bf16)a.w;
    v[4]=(bf16)b.x; v[5]=(bf16)b.y; v[6]=(bf16)b.z; v[7]=(bf16)b.w;
    *(bf16x8*)(out + (size_t)i * 8) = v;
}

// ---------------- fp32 [K][N] -> bf16 [N][K] transpose-convert ----------------
__global__ __launch_bounds__(256) void tconv(const float* __restrict__ in,
                                             bf16* __restrict__ out, int N, int K) {
    __shared__ float t[32][33];
    int bx = blockIdx.x, by = blockIdx.y;
    int tx = threadIdx.x, ty = threadIdx.y;
    int col = bx * 32 + tx;
#pragma unroll
    for (int r = 0; r < 4; ++r) {
        int row = by * 32 + ty + r * 8;
        t[ty + r * 8][tx] = in[(size_t)row * N + col];
    }
    __syncthreads();
#pragma unroll
    for (int r = 0; r < 4; ++r) {
        int n = bx * 32 + ty + r * 8;
        int k = by * 32 + tx;
        out[(size_t)n * K + k] = (bf16)t[tx][ty + r * 8];
    }
}

// ---------------- RoPE in-place on bf16 buffer (optional output scale) ------
__global__ __launch_bounds__(256) void rope_k(bf16* __restrict__ buf, int shift,
                                              int n8, float oscale) {
    int i = blockIdx.x * 256 + threadIdx.x;
    if (i >= n8) return;
    size_t base = (size_t)i * 8;
    int col = (int)(base & ((1u << shift) - 1));
    int pos = (int)((base >> shift) & (SEQ - 1));
    int d0 = col & (HD - 1);
    bf16x8 v = *(const bf16x8*)(buf + base);
    float f[8];
#pragma unroll
    for (int j = 0; j < 8; ++j) f[j] = (float)v[j];
    const float nl2t = -13.287712379549449f / 64.f;  // -log2(theta)/(HD/2)
#pragma unroll
    for (int j = 0; j < 4; ++j) {
        float inv = exp2f(nl2t * (float)((d0 >> 1) + j));
        float ang = (float)pos * inv;
        float sn, cs;
        sincosf(ang, &sn, &cs);
        float x0 = f[2 * j], x1 = f[2 * j + 1];
        f[2 * j]     = x0 * cs - x1 * sn;
        f[2 * j + 1] = x0 * sn + x1 * cs;
    }
    bf16x8 ov;
#pragma unroll
    for (int j = 0; j < 8; ++j) ov[j] = (bf16)(f[j] * oscale);
    *(bf16x8*)(buf + base) = ov;
}

// ---------------- merged K-proj + V^T-proj (one 512-block launch) ----------
// blocks 0..255:  kb [4096 x 1024] = xb * wkt^T    (by=bid>>3, bx=bid&7)
// blocks 256..511: vtb [1024 x 4096] = wvt * xb^T  (by=b2>>5, bx=b2&31)
// 2 blocks/CU -> 16 waves/CU restores the m97 wave-overlap latency hiding.
__global__ __launch_bounds__(256) void gemm_kv(const bf16* __restrict__ xb,
                                               const bf16* __restrict__ wkt,
                                               const bf16* __restrict__ wvt,
                                               bf16* __restrict__ kb,
                                               bf16* __restrict__ vtb) {
    __shared__ alignas(16) bf16 sA[2][128 * 32];
    __shared__ alignas(16) bf16 sB[2][128 * 32];
    const int tid = threadIdx.x;
    const int lane = tid & 63, wid = tid >> 6;
    const int wm = wid >> 1, wn = wid & 1;

    const bf16 *A, *Bt;
    bf16* out0;
    int N, m0, n0;
    const int bid = blockIdx.x;
    if (bid < 256) {
        A = xb; Bt = wkt; out0 = kb; N = 1024;
        m0 = (bid >> 3) * 128; n0 = (bid & 7) * 128;
    } else {
        int b2 = bid - 256;
        A = wvt; Bt = xb; out0 = vtb; N = MTOT;
        m0 = (b2 >> 5) * 128; n0 = (b2 & 31) * 128;
    }

    auto stage = [&](int buf, int kt) {
#pragma unroll
        for (int it = 0; it < 2; ++it) {
            int slot = it * 256 + tid;
            int row = slot >> 2, s = slot & 3;
            gload_lds16(A + (size_t)(m0 + row) * GK + kt * 32 + s * 8, &sA[buf][slot * 8]);
            gload_lds16(Bt + (size_t)(n0 + row) * GK + kt * 32 + s * 8, &sB[buf][slot * 8]);
        }
    };

    f32x4 acc[4][4] = {};
    stage(0, 0);
    __syncthreads();
    int cur = 0;
    for (int kt = 0; kt < GK / 32; ++kt) {
        if (kt + 1 < GK / 32) stage(cur ^ 1, kt + 1);
        bf16x8 bF[4], aF[4];
#pragma unroll
        for (int i = 0; i < 4; ++i)
            bF[i] = *(const bf16x8*)&sB[cur][(wn * 64 + i * 16 + (lane & 15)) * 32 + (lane >> 4) * 8];
#pragma unroll
        for (int i = 0; i < 4; ++i)
            aF[i] = *(const bf16x8*)&sA[cur][(wm * 64 + i * 16 + (lane & 15)) * 32 + (lane >> 4) * 8];
#pragma unroll
        for (int mi = 0; mi < 4; ++mi)
#pragma unroll
            for (int ni = 0; ni < 4; ++ni)
                acc[mi][ni] = __builtin_amdgcn_mfma_f32_16x16x32_bf16(aF[mi], bF[ni], acc[mi][ni], 0, 0, 0);
        __syncthreads();
        cur ^= 1;
    }
#pragma unroll
    for (int mi = 0; mi < 4; ++mi)
#pragma unroll
        for (int ni = 0; ni < 4; ++ni)
#pragma unroll
            for (int r = 0; r < 4; ++r) {
                int row = m0 + wm * 64 + mi * 16 + (lane >> 4) * 4 + r;
                int col = n0 + wn * 64 + ni * 16 + (lane & 15);
                out0[(size_t)row * N + col] = (bf16)acc[mi][ni][r];
            }
}

// ---------------- 256x256 deep-pipelined GEMM (8-wave, 2 phases/K-tile) -----
// Half-phase p = 2t+kh uses LDS region p mod 4 (2 buf x 2 khalf, 32KB each).
// Schedule: phase p = [ds_read region p][stage region p+3][vmcnt(8): region
// p+1 landed][s_barrier][lgkmcnt(0)][32 MFMA]. Issue->wait distance = 2
// phases (~700 cyc > HBM latency). Region p's data was guaranteed by phase
// p-1's vmcnt+barrier. Tail waits peel to 4 -> 0 (outstanding-set counted).
template <bool F32OUT>
__global__ __launch_bounds__(512, 2) void gemm8(const bf16* __restrict__ A,
                                                const bf16* __restrict__ Bt,
                                                void* __restrict__ outp, int N) {
    __shared__ alignas(16) char sA[2][2][16384];
    __shared__ alignas(16) char sB[2][2][16384];
    const int tid = threadIdx.x, lane = tid & 63;
    const int wid = tid >> 6;
    const int wm = wid >> 2, wn = wid & 3;
    const int m0 = blockIdx.y * 256, n0 = blockIdx.x * 256;
    const int lrow = lane & 15, hc = lane >> 4;
    const int rowbase = ((lrow >> 1) * 128) +
                        (((((lrow & 1) << 2) | hc) ^ (lrow >> 1)) << 4);
    const int NT = GK / 64;

    auto stageR = [&](int t, int kh) {
#pragma unroll
        for (int it = 0; it < 2; ++it) {
            int sl = it * 512 + tid;              // 16B chunk id 0..1023
            int PRr = sl >> 3, ps = sl & 7;       // pair-row, phys slot
            int lsl = ps ^ (PRr & 7);             // logical slot (involution)
            int r = PRr * 2 + (lsl >> 2);         // logical row 0..255
            int cc = lsl & 3;                     // 16B col-chunk 0..3
            size_t koff = (size_t)t * 64 + kh * 32 + cc * 8;
            gload_lds16(A + (size_t)(m0 + r) * GK + koff, &sA[t & 1][kh][sl * 16]);
            gload_lds16(Bt + (size_t)(n0 + r) * GK + koff, &sB[t & 1][kh][sl * 16]);
        }
    };

    f32x4 acc[8][4] = {};
    bf16x8 af[8], bfr[4];

    auto phread = [&](int t, int kh) {
        const char* Ab = &sA[t & 1][kh][0];
        const char* Bb = &sB[t & 1][kh][0];
#pragma unroll
        for (int ni = 0; ni < 4; ++ni)
            bfr[ni] = *(const bf16x8*)(Bb + wn * 4096 + ni * 1024 + rowbase);
#pragma unroll
        for (int mi = 0; mi < 8; ++mi)
            af[mi] = *(const bf16x8*)(Ab + wm * 8192 + mi * 1024 + rowbase);
    };
    auto phmfma = [&]() {
        __builtin_amdgcn_s_barrier();
        asm volatile("s_waitcnt lgkmcnt(0)" ::: "memory");
        __builtin_amdgcn_sched_barrier(0);
        __builtin_amdgcn_s_setprio(1);
#pragma unroll
        for (int mi = 0; mi < 8; ++mi)
#pragma unroll
            for (int ni = 0; ni < 4; ++ni)
                acc[mi][ni] = __builtin_amdgcn_mfma_f32_16x16x32_bf16(af[mi], bfr[ni], acc[mi][ni], 0, 0, 0);
        __builtin_amdgcn_s_setprio(0);
    };

    // prologue: regions 0,1,2 in flight; ensure region 0 before first reads
    stageR(0, 0); stageR(0, 1); stageR(1, 0);
    asm volatile("s_waitcnt vmcnt(8)" ::: "memory");
    __builtin_amdgcn_s_barrier();

    for (int t = 0; t < NT - 2; ++t) {
        phread(t, 0);
        stageR(t + 1, 1);
        asm volatile("s_waitcnt vmcnt(8)" ::: "memory");
        phmfma();
        phread(t, 1);
        stageR(t + 2, 0);
        asm volatile("s_waitcnt vmcnt(8)" ::: "memory");
        phmfma();
    }
    // t = NT-2
    phread(NT - 2, 0);
    stageR(NT - 1, 1);
    asm volatile("s_waitcnt vmcnt(8)" ::: "memory");
    phmfma();
    phread(NT - 2, 1);
    asm volatile("s_waitcnt vmcnt(4)" ::: "memory");
    phmfma();
    // t = NT-1
    phread(NT - 1, 0);
    asm volatile("s_waitcnt vmcnt(0)" ::: "memory");
    phmfma();
    phread(NT - 1, 1);
    phmfma();

    // epilogue
#pragma unroll
    for (int mi = 0; mi < 8; ++mi)
#pragma unroll
        for (int ni = 0; ni < 4; ++ni)
#pragma unroll
            for (int r = 0; r < 4; ++r) {
                int row = m0 + wm * 128 + mi * 16 + hc * 4 + r;
                int col = n0 + wn * 64 + ni * 16 + lrow;
                if constexpr (F32OUT)
                    ((float*)outp)[(size_t)row * N + col] = acc[mi][ni][r];
                else
                    ((bf16*)outp)[(size_t)row * N + col] = (bf16)acc[mi][ni][r];
            }
}

// ---------------- flash attention, GQA, causal ----------------
// grid: 512 = b(2) * h(32) * pair(8); 8 waves x 16 q-rows = 128 q-rows/pass;
// each block runs two passes (q-tile pr and 15-pr) -> exactly 34 KV rounds each.
// Swapped QK^T (S^T). Q pre-scaled by 1/sqrt(d)*log2(e) -> exp2-domain softmax.
// Wave-uniform diag split + defer-max (THR=8).
__global__ __launch_bounds__(512, 4) void attn_fwd(const bf16* __restrict__ q,
                                                   const bf16* __restrict__ k,
                                                   const bf16* __restrict__ vt,
                                                   bf16* __restrict__ o) {
    __shared__ alignas(16) bf16 sK[2][64 * 128];   // [kv][d], XOR-swizzled source
    __shared__ alignas(16) bf16 sV[2][128 * 64];   // [d][kv], XOR-swizzled source
    __shared__ alignas(16) bf16 sP[8][16 * 64];    // per-wave P[q][kv], swizzled
    const int tid = threadIdx.x, lane = tid & 63, wid = tid >> 6;
    const int bi = blockIdx.x;
    const int pr = bi & 7;
    const int h = (bi >> 3) & 31;
    const int b = bi >> 8;
    const int kvh = h >> 2;

    const bf16* kb0 = k + (size_t)b * SEQ * (NKV * HD) + kvh * HD;
    const bf16* vb0 = vt + (size_t)(kvh * HD) * MTOT + (size_t)b * SEQ;

    auto stage = [&](int bf, int tt) {
#pragma unroll
        for (int it = 0; it < 2; ++it) {
            int slot = it * 512 + tid;
            int row = slot >> 4, s = slot & 15;
            gload_lds16(kb0 + (size_t)(tt * 64 + row) * (NKV * HD) + ((s ^ (row & 7)) * 8),
                        &sK[bf][slot * 8]);
        }
#pragma unroll
        for (int it = 0; it < 2; ++it) {
            int slot = it * 512 + tid;
            int row = slot >> 3, s = slot & 7;
            gload_lds16(vb0 + (size_t)row * MTOT + tt * 64 + ((s ^ (row & 7)) * 8),
                        &sV[bf][slot * 8]);
        }
    };

    auto pass = [&](int qt) {
        const int qb0 = qt * 128;
        const int nt = 2 * qt + 2;
        const int qw = qb0 + wid * 16;        // wave's first q row (16-aligned)
        const bf16* qp = q + ((size_t)(b * SEQ + qw + (lane & 15))) * DIM
                           + h * HD + (lane >> 4) * 8;
        bf16x8 aQ[4];
#pragma unroll
        for (int ks = 0; ks < 4; ++ks) aQ[ks] = *(const bf16x8*)(qp + ks * 32);

        f32x4 accO[8] = {};
        float m_r = -1e30f, l_r = 0.f;   // per-lane: q-col = lane&15 (uniform over hi)
        const int qglob = qw + (lane & 15);
        char* pb = (char*)&sP[wid][0];
        const int q7s = (lane & 7) << 4;
        const int hi = lane >> 4;

        stage(0, 0);
        __syncthreads();
        int cur = 0;
        for (int tt = 0; tt < nt; ++tt) {
            if (tt + 1 < nt) stage(cur ^ 1, tt + 1);
            // skip tiles fully above this wave's rows (t0 and qw both 16-aligned)
            if (tt * 64 <= qw) {
                // S^T = mfma(K, Q): frag nt2 -> kv = tt*64+nt2*16+hi*4+r, col q = lane&15
                f32x4 accS[4] = {};
#pragma unroll
                for (int nt2 = 0; nt2 < 4; ++nt2) {
                    int kr = nt2 * 16 + (lane & 15);
#pragma unroll
                    for (int ks = 0; ks < 4; ++ks) {
                        int slog = ks * 4 + hi;
                        bf16x8 bK = *(const bf16x8*)&sK[cur][kr * 128 + ((slog ^ (kr & 7)) * 8)];
                        accS[nt2] = __builtin_amdgcn_mfma_f32_16x16x32_bf16(bK, aQ[ks], accS[nt2], 0, 0, 0);
                    }
                }

                // lane-local max over 16 kv values; mask only on diagonal tiles
                const bool diag = (tt * 64 + 63 > qw);
                float mx = -1e30f;
                if (diag) {
                    const int kvb = tt * 64 + hi * 4;
#pragma unroll
                    for (int nt2 = 0; nt2 < 4; ++nt2)
#pragma unroll
                        for (int r = 0; r < 4; ++r) {
                            float v = accS[nt2][r];
                            if (kvb + nt2 * 16 + r > qglob) v = -1e30f;
                            accS[nt2][r] = v;
                            mx = fmaxf(mx, v);
                        }
                } else {
#pragma unroll
                    for (int nt2 = 0; nt2 < 4; ++nt2)
#pragma unroll
                        for (int r = 0; r < 4; ++r) mx = fmaxf(mx, accS[nt2][r]);
                }
                mx = fmaxf(mx, __shfl_xor(mx, 16, 64));
                mx = fmaxf(mx, __shfl_xor(mx, 32, 64));

                // defer-max: only rescale when tile max advances past m_r + 8
                if (!__all(mx <= m_r + 8.f)) {
                    float mn = fmaxf(m_r, mx);
                    float al = __builtin_amdgcn_exp2f(m_r - mn);
                    m_r = mn;
                    l_r *= al;
                    float al4[4];
#pragma unroll
                    for (int r = 0; r < 4; ++r) al4[r] = __shfl(al, hi * 4 + r, 64);
#pragma unroll
                    for (int d2 = 0; d2 < 8; ++d2)
#pragma unroll
                        for (int r = 0; r < 4; ++r) accO[d2][r] *= al4[r];
                }

                float rs = 0.f;
#pragma unroll
                for (int nt2 = 0; nt2 < 4; ++nt2)
#pragma unroll
                    for (int r = 0; r < 4; ++r) {
                        float p = __builtin_amdgcn_exp2f(accS[nt2][r] - m_r);
                        accS[nt2][r] = p;
                        rs += p;
                    }
                rs += __shfl_xor(rs, 16, 64);
                rs += __shfl_xor(rs, 32, 64);
                l_r += rs;

                // P-write: lane holds 4 contiguous kv per frag -> b64 stores
#pragma unroll
                for (int nt2 = 0; nt2 < 4; ++nt2) {
                    bf16x4 pv;
                    pv[0] = (bf16)accS[nt2][0]; pv[1] = (bf16)accS[nt2][1];
                    pv[2] = (bf16)accS[nt2][2]; pv[3] = (bf16)accS[nt2][3];
                    *(bf16x4*)(pb + (lane & 15) * 128 + ((nt2 * 32 + hi * 8) ^ q7s)) = pv;
                }

                // PV: O[16 x 128] += P[16 x 64] * V[64 x 128]
                bf16x8 aP[2];
#pragma unroll
                for (int kk = 0; kk < 2; ++kk)
                    aP[kk] = *(const bf16x8*)(pb + (lane & 15) * 128 + ((kk * 64 + hi * 16) ^ q7s));
#pragma unroll
                for (int d2 = 0; d2 < 8; ++d2) {
#pragma unroll
                    for (int kk = 0; kk < 2; ++kk) {
                        int dv = d2 * 16 + (lane & 15);
                        int phys = (kk * 4 + hi) ^ (dv & 7);
                        bf16x8 bV = *(const bf16x8*)&sV[cur][dv * 64 + phys * 8];
                        accO[d2] = __builtin_amdgcn_mfma_f32_16x16x32_bf16(aP[kk], bV, accO[d2], 0, 0, 0);
                    }
                }
            }
            __syncthreads();
            cur ^= 1;
        }

        // epilogue: normalize + store bf16 (accO q-row for reg r = hi*4+r)
        float linv[4];
#pragma unroll
        for (int r = 0; r < 4; ++r) linv[r] = 1.f / __shfl(l_r, hi * 4 + r, 64);
        size_t orow = (size_t)(b * SEQ + qb0 + wid * 16 + hi * 4) * DIM
                    + h * HD + (lane & 15);
#pragma unroll
        for (int d2 = 0; d2 < 8; ++d2)
#pragma unroll
            for (int r = 0; r < 4; ++r)
                o[orow + (size_t)r * DIM + d2 * 16] = (bf16)(accO[d2][r] * linv[r]);
    };

    pass(pr);
    pass(15 - pr);
}

// ---------------- launch ----------------
extern "C" void kernel_launch(void* const* d_in, const int* in_sizes, int n_in,
                              void* d_out, int out_size, void* d_ws, size_t ws_size,
                              hipStream_t stream) {
    const float* x  = (const float*)d_in[0];
    const float* wq = (const float*)d_in[1];
    const float* wk = (const float*)d_in[2];
    const float* wv = (const float*)d_in[3];
    const float* wo = (const float*)d_in[4];
    float* out = (float*)d_out;

    char* ws = (char*)d_ws;
    size_t off = 0;
    bf16* xb  = (bf16*)(ws + off); off += (size_t)MTOT * DIM * 2;   // 32 MiB (reused as attn_out)
    bf16* wqt = (bf16*)(ws + off); off += (size_t)DIM * DIM * 2;    // 32 MiB (reused as wo_t)
    bf16* wkt = (bf16*)(ws + off); off += (size_t)1024 * DIM * 2;   // 8 MiB
    bf16* wvt = (bf16*)(ws + off); off += (size_t)1024 * DIM * 2;   // 8 MiB
    bf16* qb  = (bf16*)(ws + off); off += (size_t)MTOT * DIM * 2;   // 32 MiB
    bf16* kb  = (bf16*)(ws + off); off += (size_t)MTOT * 1024 * 2;  // 8 MiB
    bf16* vtb = (bf16*)(ws + off); off += (size_t)MTOT * 1024 * 2;  // 8 MiB  V^T [1024][4096]
    bf16* ao = xb;  // attention output reuses x_bf16

    // 1/sqrt(HD) * log2(e): folds softmax scale + exp->exp2 conversion into Q
    const float SCALE2 = 0.08838834764831845f * 1.44269504088896340f;

    dim3 tb(32, 8);
    conv_bf16<<<(MTOT * DIM / 8) / 256, 256, 0, stream>>>(x, xb, MTOT * DIM / 8);
    tconv<<<dim3(DIM / 32, DIM / 32), tb, 0, stream>>>(wq, wqt, DIM, DIM);
    tconv<<<dim3(1024 / 32, DIM / 32), tb, 0, stream>>>(wk, wkt, 1024, DIM);
    tconv<<<dim3(1024 / 32, DIM / 32), tb, 0, stream>>>(wv, wvt, 1024, DIM);

    // Q proj: 4096x4096x4096 on the 256^2 deep-pipelined kernel (256 blocks)
    gemm8<false><<<dim3(DIM / 256, MTOT / 256), 512, 0, stream>>>(xb, wqt, qb, DIM);
    // K proj + V^T proj merged: 512 blocks -> 2 blocks/CU (wave overlap)
    gemm_kv<<<512, 256, 0, stream>>>(xb, wkt, wvt, kb, vtb);

    rope_k<<<(MTOT * DIM / 8) / 256, 256, 0, stream>>>(qb, 12, MTOT * DIM / 8, SCALE2);
    rope_k<<<(MTOT * 1024 / 8) / 256, 256, 0, stream>>>(kb, 10, MTOT * 1024 / 8, 1.0f);

    tconv<<<dim3(DIM / 32, DIM / 32), tb, 0, stream>>>(wo, wqt, DIM, DIM);  // wo_t -> wqt space

    attn_fwd<<<BATCH * NH * 8, 512, 0, stream>>>(qb, kb, vtb, ao);

    // out proj: fp32 output on the 256^2 kernel
    gemm8<true><<<dim3(DIM / 256, MTOT / 256), 512, 0, stream>>>(ao, wqt, out, DIM);
}

// Round 9
// 531.349 us; speedup vs baseline: 1.1812x; 1.0209x over previous
//
#include <hip/hip_runtime.h>

#define DIM 4096
#define HD 128
#define NH 32
#define NKV 8
#define SEQ 2048
#define BATCH 2
#define MTOT (BATCH*SEQ)   // 4096 rows total
#define GK DIM             // K dim of every GEMM

typedef __bf16 bf16;
typedef __bf16 bf16x4 __attribute__((ext_vector_type(4)));
typedef __bf16 bf16x8 __attribute__((ext_vector_type(8)));
typedef float f32x4 __attribute__((ext_vector_type(4)));

__device__ __forceinline__ void gload_lds16(const void* g, void* l) {
    __builtin_amdgcn_global_load_lds(
        (const __attribute__((address_space(1))) void*)g,
        (__attribute__((address_space(3))) void*)l, 16, 0, 0);
}

// ---------------- 64x64 transpose-convert tile: fp32 [K][N] -> bf16 [N][K] --
__device__ __forceinline__ void tconv64_tile(const float* __restrict__ in,
                                             bf16* __restrict__ out,
                                             int N, int K, int bx, int by,
                                             float t[64][65], int tid) {
    int rr = tid >> 4;              // 0..15
    int cc = (tid & 15) * 4;        // 0..60
    const float* ip = in + ((size_t)(by * 64 + rr)) * N + bx * 64 + cc;
#pragma unroll
    for (int p = 0; p < 4; ++p) {
        float4 v = *(const float4*)(ip + (size_t)p * 16 * N);
        t[rr + p * 16][cc + 0] = v.x;
        t[rr + p * 16][cc + 1] = v.y;
        t[rr + p * 16][cc + 2] = v.z;
        t[rr + p * 16][cc + 3] = v.w;
    }
    __syncthreads();
#pragma unroll
    for (int p = 0; p < 4; ++p) {
        int n = rr + p * 16;
        bf16x4 o;
#pragma unroll
        for (int j = 0; j < 4; ++j) o[j] = (bf16)t[cc + j][n];
        *(bf16x4*)(out + (size_t)(bx * 64 + n) * K + by * 64 + cc) = o;
    }
}

// ---------------- fused prep: x->bf16 convert + wq/wk/wv transpose-convert --
__global__ __launch_bounds__(256) void prep(const float* __restrict__ x,
                                            const float* __restrict__ wq,
                                            const float* __restrict__ wk,
                                            const float* __restrict__ wv,
                                            bf16* __restrict__ xb,
                                            bf16* __restrict__ wqt,
                                            bf16* __restrict__ wkt,
                                            bf16* __restrict__ wvt) {
    __shared__ float t[64][65];
    const int bid = blockIdx.x, tid = threadIdx.x;
    if (bid < 8192) {                       // x convert: 8192*256*8 = MTOT*DIM
        int i = bid * 256 + tid;
        const float4* p = (const float4*)(x + (size_t)i * 8);
        float4 a = p[0], b = p[1];
        bf16x8 v;
        v[0]=(bf16)a.x; v[1]=(bf16)a.y; v[2]=(bf16)a.z; v[3]=(bf16)a.w;
        v[4]=(bf16)b.x; v[5]=(bf16)b.y; v[6]=(bf16)b.z; v[7]=(bf16)b.w;
        *(bf16x8*)(xb + (size_t)i * 8) = v;
    } else if (bid < 8192 + 4096) {         // wq: 64x64 tiles
        int b2 = bid - 8192;
        tconv64_tile(wq, wqt, DIM, DIM, b2 & 63, b2 >> 6, t, tid);
    } else if (bid < 8192 + 4096 + 1024) {  // wk
        int b2 = bid - (8192 + 4096);
        tconv64_tile(wk, wkt, 1024, DIM, b2 & 15, b2 >> 4, t, tid);
    } else {                                // wv
        int b2 = bid - (8192 + 4096 + 1024);
        tconv64_tile(wv, wvt, 1024, DIM, b2 & 15, b2 >> 4, t, tid);
    }
}

// ---------------- standalone transpose-convert (wo, after Q-proj) ----------
__global__ __launch_bounds__(256) void tconv64(const float* __restrict__ in,
                                               bf16* __restrict__ out, int N, int K) {
    __shared__ float t[64][65];
    tconv64_tile(in, out, N, K, blockIdx.x, blockIdx.y, t, threadIdx.x);
}

// ---------------- RoPE on qb and kb in one launch ---------------------------
__global__ __launch_bounds__(256) void rope_both(bf16* __restrict__ qb,
                                                 bf16* __restrict__ kb, float qs) {
    const int bid = blockIdx.x, tid = threadIdx.x;
    bf16* buf; int shift; float os; int i;
    if (bid < 8192) { buf = qb; shift = 12; os = qs; i = bid * 256 + tid; }
    else            { buf = kb; shift = 10; os = 1.f; i = (bid - 8192) * 256 + tid; }
    size_t base = (size_t)i * 8;
    int col = (int)(base & ((1u << shift) - 1));
    int pos = (int)((base >> shift) & (SEQ - 1));
    int d0 = col & (HD - 1);
    bf16x8 v = *(const bf16x8*)(buf + base);
    float f[8];
#pragma unroll
    for (int j = 0; j < 8; ++j) f[j] = (float)v[j];
    const float nl2t = -13.287712379549449f / 64.f;  // -log2(theta)/(HD/2)
#pragma unroll
    for (int j = 0; j < 4; ++j) {
        float inv = exp2f(nl2t * (float)((d0 >> 1) + j));
        float ang = (float)pos * inv;
        float sn, cs;
        sincosf(ang, &sn, &cs);
        float x0 = f[2 * j], x1 = f[2 * j + 1];
        f[2 * j]     = x0 * cs - x1 * sn;
        f[2 * j + 1] = x0 * sn + x1 * cs;
    }
    bf16x8 ov;
#pragma unroll
    for (int j = 0; j < 8; ++j) ov[j] = (bf16)(f[j] * os);
    *(bf16x8*)(buf + base) = ov;
}

// ---------------- merged K-proj + V^T-proj (one 512-block launch) ----------
__global__ __launch_bounds__(256) void gemm_kv(const bf16* __restrict__ xb,
                                               const bf16* __restrict__ wkt,
                                               const bf16* __restrict__ wvt,
                                               bf16* __restrict__ kb,
                                               bf16* __restrict__ vtb) {
    __shared__ alignas(16) bf16 sA[2][128 * 32];
    __shared__ alignas(16) bf16 sB[2][128 * 32];
    const int tid = threadIdx.x;
    const int lane = tid & 63, wid = tid >> 6;
    const int wm = wid >> 1, wn = wid & 1;

    const bf16 *A, *Bt;
    bf16* out0;
    int N, m0, n0;
    const int bid = blockIdx.x;
    if (bid < 256) {
        A = xb; Bt = wkt; out0 = kb; N = 1024;
        m0 = (bid >> 3) * 128; n0 = (bid & 7) * 128;
    } else {
        int b2 = bid - 256;
        A = wvt; Bt = xb; out0 = vtb; N = MTOT;
        m0 = (b2 >> 5) * 128; n0 = (b2 & 31) * 128;
    }

    auto stage = [&](int buf, int kt) {
#pragma unroll
        for (int it = 0; it < 2; ++it) {
            int slot = it * 256 + tid;
            int row = slot >> 2, s = slot & 3;
            gload_lds16(A + (size_t)(m0 + row) * GK + kt * 32 + s * 8, &sA[buf][slot * 8]);
            gload_lds16(Bt + (size_t)(n0 + row) * GK + kt * 32 + s * 8, &sB[buf][slot * 8]);
        }
    };

    f32x4 acc[4][4] = {};
    stage(0, 0);
    __syncthreads();
    int cur = 0;
    for (int kt = 0; kt < GK / 32; ++kt) {
        if (kt + 1 < GK / 32) stage(cur ^ 1, kt + 1);
        bf16x8 bF[4], aF[4];
#pragma unroll
        for (int i = 0; i < 4; ++i)
            bF[i] = *(const bf16x8*)&sB[cur][(wn * 64 + i * 16 + (lane & 15)) * 32 + (lane >> 4) * 8];
#pragma unroll
        for (int i = 0; i < 4; ++i)
            aF[i] = *(const bf16x8*)&sA[cur][(wm * 64 + i * 16 + (lane & 15)) * 32 + (lane >> 4) * 8];
#pragma unroll
        for (int mi = 0; mi < 4; ++mi)
#pragma unroll
            for (int ni = 0; ni < 4; ++ni)
                acc[mi][ni] = __builtin_amdgcn_mfma_f32_16x16x32_bf16(aF[mi], bF[ni], acc[mi][ni], 0, 0, 0);
        __syncthreads();
        cur ^= 1;
    }
#pragma unroll
    for (int mi = 0; mi < 4; ++mi)
#pragma unroll
        for (int ni = 0; ni < 4; ++ni)
#pragma unroll
            for (int r = 0; r < 4; ++r) {
                int row = m0 + wm * 64 + mi * 16 + (lane >> 4) * 4 + r;
                int col = n0 + wn * 64 + ni * 16 + (lane & 15);
                out0[(size_t)row * N + col] = (bf16)acc[mi][ni][r];
            }
}

// ---------------- 256x256 deep-pipelined GEMM (8-wave, 2 phases/K-tile) -----
// Phase p: [12 ds_read region p][stage region p+3][vmcnt(8): region p+1
// landed][s_barrier + compiler fence][setprio + 32 MFMA with COMPILER-
// PROGRESSIVE lgkmcnt waits (no manual drain — reads overlap MFMA issue)].
// Counted vmcnt never 0 except the tail. Region p+1's data: every wave's
// loads for it retired at that wave's phase-p vmcnt, all before barrier(p).
template <bool F32OUT>
__global__ __launch_bounds__(512, 2) void gemm8(const bf16* __restrict__ A,
                                                const bf16* __restrict__ Bt,
                                                void* __restrict__ outp, int N) {
    __shared__ alignas(16) char sA[2][2][16384];
    __shared__ alignas(16) char sB[2][2][16384];
    const int tid = threadIdx.x, lane = tid & 63;
    const int wid = tid >> 6;
    const int wm = wid >> 2, wn = wid & 3;
    const int m0 = blockIdx.y * 256, n0 = blockIdx.x * 256;
    const int lrow = lane & 15, hc = lane >> 4;
    const int rowbase = ((lrow >> 1) * 128) +
                        (((((lrow & 1) << 2) | hc) ^ (lrow >> 1)) << 4);
    const int NT = GK / 64;

    auto stageR = [&](int t, int kh) {
#pragma unroll
        for (int it = 0; it < 2; ++it) {
            int sl = it * 512 + tid;              // 16B chunk id 0..1023
            int PRr = sl >> 3, ps = sl & 7;       // pair-row, phys slot
            int lsl = ps ^ (PRr & 7);             // logical slot (involution)
            int r = PRr * 2 + (lsl >> 2);         // logical row 0..255
            int cc = lsl & 3;                     // 16B col-chunk 0..3
            size_t koff = (size_t)t * 64 + kh * 32 + cc * 8;
            gload_lds16(A + (size_t)(m0 + r) * GK + koff, &sA[t & 1][kh][sl * 16]);
            gload_lds16(Bt + (size_t)(n0 + r) * GK + koff, &sB[t & 1][kh][sl * 16]);
        }
    };

    f32x4 acc[8][4] = {};
    bf16x8 af[8], bfr[4];

    auto phread = [&](int t, int kh) {
        const char* Ab = &sA[t & 1][kh][0];
        const char* Bb = &sB[t & 1][kh][0];
#pragma unroll
        for (int ni = 0; ni < 4; ++ni)
            bfr[ni] = *(const bf16x8*)(Bb + wn * 4096 + ni * 1024 + rowbase);
#pragma unroll
        for (int mi = 0; mi < 8; ++mi)
            af[mi] = *(const bf16x8*)(Ab + wm * 8192 + mi * 1024 + rowbase);
    };
    auto phmfma = [&]() {
        __builtin_amdgcn_s_barrier();
        asm volatile("" ::: "memory");   // compiler fence: no mem op crosses barrier
        __builtin_amdgcn_s_setprio(1);
#pragma unroll
        for (int mi = 0; mi < 8; ++mi)
#pragma unroll
            for (int ni = 0; ni < 4; ++ni)
                acc[mi][ni] = __builtin_amdgcn_mfma_f32_16x16x32_bf16(af[mi], bfr[ni], acc[mi][ni], 0, 0, 0);
        __builtin_amdgcn_s_setprio(0);
    };

    // prologue: regions 0,1,2 in flight; ensure region 0 before first reads
    stageR(0, 0); stageR(0, 1); stageR(1, 0);
    asm volatile("s_waitcnt vmcnt(8)" ::: "memory");
    __builtin_amdgcn_s_barrier();
    asm volatile("" ::: "memory");

    for (int t = 0; t < NT - 2; ++t) {
        phread(t, 0);
        stageR(t + 1, 1);
        asm volatile("s_waitcnt vmcnt(8)" ::: "memory");
        phmfma();
        phread(t, 1);
        stageR(t + 2, 0);
        asm volatile("s_waitcnt vmcnt(8)" ::: "memory");
        phmfma();
    }
    // t = NT-2
    phread(NT - 2, 0);
    stageR(NT - 1, 1);
    asm volatile("s_waitcnt vmcnt(8)" ::: "memory");
    phmfma();
    phread(NT - 2, 1);
    asm volatile("s_waitcnt vmcnt(4)" ::: "memory");
    phmfma();
    // t = NT-1
    phread(NT - 1, 0);
    asm volatile("s_waitcnt vmcnt(0)" ::: "memory");
    phmfma();
    phread(NT - 1, 1);
    phmfma();

    // epilogue
#pragma unroll
    for (int mi = 0; mi < 8; ++mi)
#pragma unroll
        for (int ni = 0; ni < 4; ++ni)
#pragma unroll
            for (int r = 0; r < 4; ++r) {
                int row = m0 + wm * 128 + mi * 16 + hc * 4 + r;
                int col = n0 + wn * 64 + ni * 16 + lrow;
                if constexpr (F32OUT)
                    ((float*)outp)[(size_t)row * N + col] = acc[mi][ni][r];
                else
                    ((bf16*)outp)[(size_t)row * N + col] = (bf16)acc[mi][ni][r];
            }
}

// ---------------- flash attention, GQA, causal ----------------
// grid: 512 = b(2) * h(32) * pair(8); 8 waves x 16 q-rows = 128 q-rows/pass;
// each block runs two passes (q-tile pr and 15-pr) -> exactly 34 KV rounds each.
// Swapped QK^T (S^T). Q pre-scaled by 1/sqrt(d)*log2(e) -> exp2-domain softmax.
// Wave-uniform diag split + defer-max (THR=8).
__global__ __launch_bounds__(512, 4) void attn_fwd(const bf16* __restrict__ q,
                                                   const bf16* __restrict__ k,
                                                   const bf16* __restrict__ vt,
                                                   bf16* __restrict__ o) {
    __shared__ alignas(16) bf16 sK[2][64 * 128];   // [kv][d], XOR-swizzled source
    __shared__ alignas(16) bf16 sV[2][128 * 64];   // [d][kv], XOR-swizzled source
    __shared__ alignas(16) bf16 sP[8][16 * 64];    // per-wave P[q][kv], swizzled
    const int tid = threadIdx.x, lane = tid & 63, wid = tid >> 6;
    const int bi = blockIdx.x;
    const int pr = bi & 7;
    const int h = (bi >> 3) & 31;
    const int b = bi >> 8;
    const int kvh = h >> 2;

    const bf16* kb0 = k + (size_t)b * SEQ * (NKV * HD) + kvh * HD;
    const bf16* vb0 = vt + (size_t)(kvh * HD) * MTOT + (size_t)b * SEQ;

    auto stage = [&](int bf, int tt) {
#pragma unroll
        for (int it = 0; it < 2; ++it) {
            int slot = it * 512 + tid;
            int row = slot >> 4, s = slot & 15;
            gload_lds16(kb0 + (size_t)(tt * 64 + row) * (NKV * HD) + ((s ^ (row & 7)) * 8),
                        &sK[bf][slot * 8]);
        }
#pragma unroll
        for (int it = 0; it < 2; ++it) {
            int slot = it * 512 + tid;
            int row = slot >> 3, s = slot & 7;
            gload_lds16(vb0 + (size_t)row * MTOT + tt * 64 + ((s ^ (row & 7)) * 8),
                        &sV[bf][slot * 8]);
        }
    };

    auto pass = [&](int qt) {
        const int qb0 = qt * 128;
        const int nt = 2 * qt + 2;
        const int qw = qb0 + wid * 16;        // wave's first q row (16-aligned)
        const bf16* qp = q + ((size_t)(b * SEQ + qw + (lane & 15))) * DIM
                           + h * HD + (lane >> 4) * 8;
        bf16x8 aQ[4];
#pragma unroll
        for (int ks = 0; ks < 4; ++ks) aQ[ks] = *(const bf16x8*)(qp + ks * 32);

        f32x4 accO[8] = {};
        float m_r = -1e30f, l_r = 0.f;   // per-lane: q-col = lane&15 (uniform over hi)
        const int qglob = qw + (lane & 15);
        char* pb = (char*)&sP[wid][0];
        const int q7s = (lane & 7) << 4;
        const int hi = lane >> 4;

        stage(0, 0);
        __syncthreads();
        int cur = 0;
        for (int tt = 0; tt < nt; ++tt) {
            if (tt + 1 < nt) stage(cur ^ 1, tt + 1);
            // skip tiles fully above this wave's rows (t0 and qw both 16-aligned)
            if (tt * 64 <= qw) {
                // S^T = mfma(K, Q): frag nt2 -> kv = tt*64+nt2*16+hi*4+r, col q = lane&15
                f32x4 accS[4] = {};
#pragma unroll
                for (int nt2 = 0; nt2 < 4; ++nt2) {
                    int kr = nt2 * 16 + (lane & 15);
#pragma unroll
                    for (int ks = 0; ks < 4; ++ks) {
                        int slog = ks * 4 + hi;
                        bf16x8 bK = *(const bf16x8*)&sK[cur][kr * 128 + ((slog ^ (kr & 7)) * 8)];
                        accS[nt2] = __builtin_amdgcn_mfma_f32_16x16x32_bf16(bK, aQ[ks], accS[nt2], 0, 0, 0);
                    }
                }

                // lane-local max over 16 kv values; mask only on diagonal tiles
                const bool diag = (tt * 64 + 63 > qw);
                float mx = -1e30f;
                if (diag) {
                    const int kvb = tt * 64 + hi * 4;
#pragma unroll
                    for (int nt2 = 0; nt2 < 4; ++nt2)
#pragma unroll
                        for (int r = 0; r < 4; ++r) {
                            float v = accS[nt2][r];
                            if (kvb + nt2 * 16 + r > qglob) v = -1e30f;
                            accS[nt2][r] = v;
                            mx = fmaxf(mx, v);
                        }
                } else {
#pragma unroll
                    for (int nt2 = 0; nt2 < 4; ++nt2)
#pragma unroll
                        for (int r = 0; r < 4; ++r) mx = fmaxf(mx, accS[nt2][r]);
                }
                mx = fmaxf(mx, __shfl_xor(mx, 16, 64));
                mx = fmaxf(mx, __shfl_xor(mx, 32, 64));

                // defer-max: only rescale when tile max advances past m_r + 8
                if (!__all(mx <= m_r + 8.f)) {
                    float mn = fmaxf(m_r, mx);
                    float al = __builtin_amdgcn_exp2f(m_r - mn);
                    m_r = mn;
                    l_r *= al;
                    float al4[4];
#pragma unroll
                    for (int r = 0; r < 4; ++r) al4[r] = __shfl(al, hi * 4 + r, 64);
#pragma unroll
                    for (int d2 = 0; d2 < 8; ++d2)
#pragma unroll
                        for (int r = 0; r < 4; ++r) accO[d2][r] *= al4[r];
                }

                float rs = 0.f;
#pragma unroll
                for (int nt2 = 0; nt2 < 4; ++nt2)
#pragma unroll
                    for (int r = 0; r < 4; ++r) {
                        float p = __builtin_amdgcn_exp2f(accS[nt2][r] - m_r);
                        accS[nt2][r] = p;
                        rs += p;
                    }
                rs += __shfl_xor(rs, 16, 64);
                rs += __shfl_xor(rs, 32, 64);
                l_r += rs;

                // P-write: lane holds 4 contiguous kv per frag -> b64 stores
#pragma unroll
                for (int nt2 = 0; nt2 < 4; ++nt2) {
                    bf16x4 pv;
                    pv[0] = (bf16)accS[nt2][0]; pv[1] = (bf16)accS[nt2][1];
                    pv[2] = (bf16)accS[nt2][2]; pv[3] = (bf16)accS[nt2][3];
                    *(bf16x4*)(pb + (lane & 15) * 128 + ((nt2 * 32 + hi * 8) ^ q7s)) = pv;
                }

                // PV: O[16 x 128] += P[16 x 64] * V[64 x 128]
                bf16x8 aP[2];
#pragma unroll
                for (int kk = 0; kk < 2; ++kk)
                    aP[kk] = *(const bf16x8*)(pb + (lane & 15) * 128 + ((kk * 64 + hi * 16) ^ q7s));
#pragma unroll
                for (int d2 = 0; d2 < 8; ++d2) {
#pragma unroll
                    for (int kk = 0; kk < 2; ++kk) {
                        int dv = d2 * 16 + (lane & 15);
                        int phys = (kk * 4 + hi) ^ (dv & 7);
                        bf16x8 bV = *(const bf16x8*)&sV[cur][dv * 64 + phys * 8];
                        accO[d2] = __builtin_amdgcn_mfma_f32_16x16x32_bf16(aP[kk], bV, accO[d2], 0, 0, 0);
                    }
                }
            }
            __syncthreads();
            cur ^= 1;
        }

        // epilogue: normalize + store bf16 (accO q-row for reg r = hi*4+r)
        float linv[4];
#pragma unroll
        for (int r = 0; r < 4; ++r) linv[r] = 1.f / __shfl(l_r, hi * 4 + r, 64);
        size_t orow = (size_t)(b * SEQ + qb0 + wid * 16 + hi * 4) * DIM
                    + h * HD + (lane & 15);
#pragma unroll
        for (int d2 = 0; d2 < 8; ++d2)
#pragma unroll
            for (int r = 0; r < 4; ++r)
                o[orow + (size_t)r * DIM + d2 * 16] = (bf16)(accO[d2][r] * linv[r]);
    };

    pass(pr);
    pass(15 - pr);
}

// ---------------- launch ----------------
extern "C" void kernel_launch(void* const* d_in, const int* in_sizes, int n_in,
                              void* d_out, int out_size, void* d_ws, size_t ws_size,
                              hipStream_t stream) {
    const float* x  = (const float*)d_in[0];
    const float* wq = (const float*)d_in[1];
    const float* wk = (const float*)d_in[2];
    const float* wv = (const float*)d_in[3];
    const float* wo = (const float*)d_in[4];
    float* out = (float*)d_out;

    char* ws = (char*)d_ws;
    size_t off = 0;
    bf16* xb  = (bf16*)(ws + off); off += (size_t)MTOT * DIM * 2;   // 32 MiB (reused as attn_out)
    bf16* wqt = (bf16*)(ws + off); off += (size_t)DIM * DIM * 2;    // 32 MiB (reused as wo_t)
    bf16* wkt = (bf16*)(ws + off); off += (size_t)1024 * DIM * 2;   // 8 MiB
    bf16* wvt = (bf16*)(ws + off); off += (size_t)1024 * DIM * 2;   // 8 MiB
    bf16* qb  = (bf16*)(ws + off); off += (size_t)MTOT * DIM * 2;   // 32 MiB
    bf16* kb  = (bf16*)(ws + off); off += (size_t)MTOT * 1024 * 2;  // 8 MiB
    bf16* vtb = (bf16*)(ws + off); off += (size_t)MTOT * 1024 * 2;  // 8 MiB  V^T [1024][4096]
    bf16* ao = xb;  // attention output reuses x_bf16

    // 1/sqrt(HD) * log2(e): folds softmax scale + exp->exp2 conversion into Q
    const float SCALE2 = 0.08838834764831845f * 1.44269504088896340f;

    // fused prep: x convert (8192) + wq (4096) + wk (1024) + wv (1024)
    prep<<<8192 + 4096 + 1024 + 1024, 256, 0, stream>>>(x, wq, wk, wv, xb, wqt, wkt, wvt);

    // Q proj: 4096x4096x4096 on the 256^2 deep-pipelined kernel (256 blocks)
    gemm8<false><<<dim3(DIM / 256, MTOT / 256), 512, 0, stream>>>(xb, wqt, qb, DIM);
    // K proj + V^T proj merged: 512 blocks -> 2 blocks/CU (wave overlap)
    gemm_kv<<<512, 256, 0, stream>>>(xb, wkt, wvt, kb, vtb);

    // RoPE on qb (8192 blocks) + kb (2048 blocks) in one launch
    rope_both<<<8192 + 2048, 256, 0, stream>>>(qb, kb, SCALE2);

    // wo transpose -> wqt space (free after Q proj)
    tconv64<<<dim3(DIM / 64, DIM / 64), 256, 0, stream>>>(wo, wqt, DIM, DIM);

    attn_fwd<<<BATCH * NH * 8, 512, 0, stream>>>(qb, kb, vtb, ao);

    // out proj: fp32 output on the 256^2 kernel
    gemm8<true><<<dim3(DIM / 256, MTOT / 256), 512, 0, stream>>>(ao, wqt, out, DIM);
}